// Round 2
// baseline (392.786 us; speedup 1.0000x reference)
//
#include <hip/hip_runtime.h>
#include <cstdint>

// ---------------------------------------------------------------------------
// AdaptiveMixing fused kernel set, R7.
// R7 = R6 structure (outproj fused into `fused`, y2f eliminated) with the
// three R6 risk factors reverted to R5-proven forms after the NaN failure:
//  - manual RNE f2b/pk2 (no v_cvt_pk_bf16_f32 inline asm)
//  - __launch_bounds__(512, 2)  (no forced 128-VGPR cap -> no spill risk)
//  - g2t tile LINEAR [t][d16][o] (no XOR swizzle; ~16-way conflict on the
//    outacc b128 reads accepted this round; swizzle returns as isolated A/B)
// Structure:
//  - spatial-GELU output -> 16 KB LDS tile g2t (instead of 67 MB global y2f)
//  - at each even dt (past the trailing barrier of dt-1) every wave
//    accumulates aco[2] = 16tok x 32q against wop B-frags. A contract is the
//    old y2f contract: row = t, k = o, kc5 = dt2*16 + d16.
// Layouts (from R4/R5):
//   w2p  [cb][d][ks][lane][8], w2sp [g][ks][lane][8], w1p [nb][ks][lane][8],
//   wop  [kc5][nb][lane][8]  (kc5 = dt2*16+d16, k'' = o)
// MFMA 16x16x32_bf16: A/B: idx lane&15, k=(lane>>4)*8+j; C/D: col=lane&15,
// row=(lane>>4)*4+i.
// ---------------------------------------------------------------------------

typedef __bf16 bf16x8 __attribute__((ext_vector_type(8)));
typedef float  f32x4  __attribute__((ext_vector_type(4)));
typedef unsigned short ushort;
typedef ushort ushort8 __attribute__((ext_vector_type(8)));

#define TW 16     // tokens per fused workgroup

__device__ __forceinline__ ushort f2b(float f) {
    union { float f; uint32_t u; } v; v.f = f;
    uint32_t u = v.u;
    u += 0x7fffu + ((u >> 16) & 1u);   // RNE
    return (ushort)(u >> 16);
}
__device__ __forceinline__ uint32_t pk2(float a, float b) {
    return (uint32_t)f2b(a) | ((uint32_t)f2b(b) << 16);
}
// Abramowitz-Stegun 7.1.26 erf (|err|<=1.5e-7), branchless; gelu exact form.
__device__ __forceinline__ float gelu_fast(float x) {
    float z = fabsf(x) * 0.70710678118654752440f;
    float t = __builtin_amdgcn_rcpf(fmaf(0.3275911f, z, 1.0f));
    float p = t * fmaf(t, fmaf(t, fmaf(t, fmaf(t, 1.061405429f, -1.453152027f),
                                       1.421413741f), -0.284496736f), 0.254829592f);
    float e = __expf(-z * z);
    float erfv = copysignf(fmaf(-p, e, 1.0f), x);
    return 0.5f * x * (1.0f + erfv);
}

// ---------------------------------------------------------------------------
// prep: fragment-linear bf16 permutes. 4096 x 256 threads.
__global__ void prep(const float* __restrict__ w2, const float* __restrict__ w1,
                     const float* __restrict__ wo, const float* __restrict__ b2,
                     ushort* __restrict__ w2p, ushort* __restrict__ w2sp,
                     ushort* __restrict__ w1p, ushort* __restrict__ wop,
                     float* __restrict__ b2t) {
    int i = blockIdx.x * 256 + threadIdx.x;          // 1,048,576 threads
    {   // w2p: channel rows 0..16383. i = cb<<17 | d<<10 | ks<<9 | l<<3 | j
        int j = i & 7, l = (i >> 3) & 63, ks = (i >> 9) & 1;
        int d = (i >> 10) & 127, cb = (i >> 17) & 7;
        w2p[i] = f2b(w2[(size_t)((cb * 16 + (l & 15)) * 128 + d) * 64 +
                        ks * 32 + (l >> 4) * 8 + j]);
    }
    {   // wop: i = kc5<<13 | nb<<9 | l<<3 | j ; k'' = o = (l>>4)*8 + j
        int j = i & 7, l = (i >> 3) & 63, nb = (i >> 9) & 15, kc5 = (i >> 13) & 127;
        int o = (l >> 4) * 8 + j, q = nb * 16 + (l & 15);
        int d16 = kc5 & 15, dt2 = kc5 >> 4;
        wop[i] = f2b(wo[(size_t)q * 4096 + o * 128 + dt2 * 16 + d16]);
    }
    if (i < 65536) {  // w2sp: sm rows 16384..17407. i = g<<10 | ks<<9 | l<<3 | j
        int j = i & 7, l = (i >> 3) & 63, ks = (i >> 9) & 1, g = (i >> 10) & 63;
        w2sp[i] = f2b(w2[(size_t)(16384 + g * 16 + (l & 15)) * 64 +
                         ks * 32 + (l >> 4) * 8 + j]);
    }
    if (i < 16384) {  // w1p: i = nb<<12 | ks<<9 | l<<3 | j
        int j = i & 7, l = (i >> 3) & 63, ks = (i >> 9) & 7, nb = i >> 12;
        w1p[i] = f2b(w1[(nb * 16 + (l & 15)) * 256 + ks * 32 + (l >> 4) * 8 + j]);
        b2t[i] = b2[(i & 127) * 128 + (i >> 7)];      // [d][c]
    }
}

// ---------------------------------------------------------------------------
__launch_bounds__(512, 2)
__global__ void fused(const float* __restrict__ sampled, const float* __restrict__ query,
                      const float* __restrict__ ln_w, const float* __restrict__ ln_b,
                      const float* __restrict__ b1, const float* __restrict__ b2,
                      const float* __restrict__ m_beta, const float* __restrict__ s_beta,
                      const ushort* __restrict__ w2p, const ushort* __restrict__ w2sp,
                      const ushort* __restrict__ w1p, const float* __restrict__ b2t,
                      const ushort* __restrict__ wop, const float* __restrict__ bo,
                      float* __restrict__ out) {
    __shared__ ushort Hb[TW * 64];                       // h bf16 [t][64]
    __shared__ union {
        ushort qn[TW * 264];                             // phase 1: LN out
        ushort smT[TW * 1032];                           // phase 2: sm [t][o*32+p]
        struct {
            ushort pt[TW * 1032];                        // [t][chunk(c>>3,dd)][c&7]
            ushort g1s[TW * 640];                        // [t][d16*40+p]
        } mp;                                            // main loop
    } U;
    // g2 tile, lives across 2 barriers (spatial writes odd dt, OUTACC reads
    // next even dt) -> own allocation. LINEAR [t][d16][o] bf16 this round.
    __shared__ __align__(16) ushort g2t[TW * 16 * 32];   // 16384 B
    __shared__ float mb_s[128];
    __shared__ float sb_s[32];

    const int tid  = threadIdx.x;
    const int wv   = tid >> 6;          // wave 0..7
    const int lane = tid & 63;
    const int lq   = lane >> 4;         // quad
    const int ln16 = lane & 15;
    const int tok0 = blockIdx.x * TW;

    if (tid < 128) mb_s[tid] = m_beta[tid];
    else if (tid < 160) sb_s[tid - 128] = s_beta[tid - 128];

    // ---- step 1: LayerNorm, 2 tokens per wave; qn -> LDS bf16 (row 264)
    for (int tt = 0; tt < 2; ++tt) {
        int t = wv * 2 + tt;
        const float* q = query + (size_t)(tok0 + t) * 256;
        float2 a = *(const float2*)(q + 2 * lane);
        float2 b = *(const float2*)(q + 128 + 2 * lane);
        float s = a.x + a.y + b.x + b.y;
        for (int off = 1; off < 64; off <<= 1) s += __shfl_xor(s, off);
        float mu = s * (1.0f / 256.0f);
        float d0 = a.x - mu, d1 = a.y - mu, d2 = b.x - mu, d3 = b.y - mu;
        float ss = d0 * d0 + d1 * d1 + d2 * d2 + d3 * d3;
        for (int off = 1; off < 64; off <<= 1) ss += __shfl_xor(ss, off);
        float rstd = rsqrtf(ss * (1.0f / 256.0f) + 1e-6f);
        int i0 = 2 * lane, i1 = 2 * lane + 128;
        float q0 = d0 * rstd * ln_w[i0]     + ln_b[i0];
        float q1 = d1 * rstd * ln_w[i0 + 1] + ln_b[i0 + 1];
        float q2 = d2 * rstd * ln_w[i1]     + ln_b[i1];
        float q3 = d3 * rstd * ln_w[i1 + 1] + ln_b[i1 + 1];
        *(uint32_t*)&U.qn[t * 264 + i0] = pk2(q0, q1);
        *(uint32_t*)&U.qn[t * 264 + i1] = pk2(q2, q3);
    }
    __syncthreads();

    // ---- step 2: h[16 tok][64] = qn @ w1^T + b1 (waves 0..3)
    if (wv < 4) {
        int nb = wv;
        f32x4 acc = {0.0f, 0.0f, 0.0f, 0.0f};
        for (int ks = 0; ks < 8; ++ks) {
            bf16x8 afr = *(const bf16x8*)&U.qn[ln16 * 264 + ks * 32 + lq * 8];
            bf16x8 bfr = *(const bf16x8*)&w1p[(nb * 8 + ks) * 512 + lane * 8];
            acc = __builtin_amdgcn_mfma_f32_16x16x32_bf16(afr, bfr, acc, 0, 0, 0);
        }
        float bias = b1[nb * 16 + ln16];
        for (int i = 0; i < 4; ++i) {
            int t = lq * 4 + i;                      // D row = token
            Hb[t * 64 + nb * 16 + ln16] = f2b(acc[i] + bias);
        }
    }
    __syncthreads();

    // ---- step 3: H B-frags; sm generation -> smT; x A-frag hoist
    bf16x8 hfr[2];
    hfr[0] = *(const bf16x8*)&Hb[ln16 * 64 + 0 + lq * 8];
    hfr[1] = *(const bf16x8*)&Hb[ln16 * 64 + 32 + lq * 8];

    for (int gi = 0; gi < 8; ++gi) {                 // sm rows 16384 + g*16 + m
        int g = wv * 8 + gi;
        f32x4 acc = *(const f32x4*)&b2[16384 + g * 16 + lq * 4];
        for (int ks = 0; ks < 2; ++ks) {
            bf16x8 afr = *(const bf16x8*)&w2sp[(g * 2 + ks) * 512 + lane * 8];
            acc = __builtin_amdgcn_mfma_f32_16x16x32_bf16(afr, hfr[ks], acc, 0, 0, 0);
        }
        int o = g >> 1;
        int p0 = (g & 1) * 16 + lq * 4;
        uint2 wr;
        wr.x = pk2(acc[0], acc[1]);
        wr.y = pk2(acc[2], acc[3]);
        *(uint2*)&U.smT[ln16 * 1032 + o * 32 + p0] = wr;   // token-major
    }

    bf16x8 xa[2][2][4];                              // x A-frags [tt][p-half][ks]
    for (int tt = 0; tt < 2; ++tt) {
        const float* xp = sampled + (size_t)(tok0 + wv * 2 + tt) * 4096;
        for (int mt = 0; mt < 2; ++mt) {
            int p = mt * 16 + ln16;
            for (int ks = 0; ks < 4; ++ks) {
                int c = ks * 32 + lq * 8;
                float4 lo = *(const float4*)(xp + p * 128 + c);
                float4 hi = *(const float4*)(xp + p * 128 + c + 4);
                ushort8 u;
                u[0] = f2b(lo.x); u[1] = f2b(lo.y); u[2] = f2b(lo.z); u[3] = f2b(lo.w);
                u[4] = f2b(hi.x); u[5] = f2b(hi.y); u[6] = f2b(hi.z); u[7] = f2b(hi.w);
                xa[tt][mt][ks] = __builtin_bit_cast(bf16x8, u);
            }
        }
    }
    __syncthreads();

    // ---- step 4: sm A-frags (K=32) for this wave's 2 tokens
    bf16x8 sa[2][2];
    for (int tt = 0; tt < 2; ++tt) {
        int t = wv * 2 + tt;
        for (int mt = 0; mt < 2; ++mt)
            sa[tt][mt] = *(const bf16x8*)&U.smT[t * 1032 + (mt * 16 + ln16) * 32 + lq * 8];
    }
    __syncthreads();    // smT dead; pt/g1s alias it from here on

    // out-projection accumulator: 16 tok x 32 q per wave (nb = 2wv, 2wv+1)
    f32x4 aco[2] = {(f32x4){0.0f, 0.0f, 0.0f, 0.0f}, (f32x4){0.0f, 0.0f, 0.0f, 0.0f}};

    // OUTACC(dt2): aco += g2t(tile dt2) @ wop. A: row=t(ln16), k=o(lq*8+j);
    // B: wop[kc5=dt2*16+d16][nb][lane][8]. K=32 per d16 step, 16 steps.
    auto outacc = [&](int dt2) {
        const ushort* wb = wop + ((size_t)(dt2 * 16) * 16 + wv * 2) * 512 + lane * 8;
        const char* gpb = (const char*)g2t + ln16 * 1024 + lq * 16;
        for (int d16 = 0; d16 < 16; ++d16) {
            bf16x8 afr = *(const bf16x8*)(gpb + d16 * 64);
            bf16x8 bf0 = *(const bf16x8*)(wb + (size_t)d16 * 8192);
            bf16x8 bf1 = *(const bf16x8*)(wb + (size_t)d16 * 8192 + 512);
            aco[0] = __builtin_amdgcn_mfma_f32_16x16x32_bf16(afr, bf0, aco[0], 0, 0, 0);
            aco[1] = __builtin_amdgcn_mfma_f32_16x16x32_bf16(afr, bf1, aco[1], 0, 0, 0);
        }
    };

    // ---- main loop over 16 d-tiles of width 8; spatial every 2nd tile
    for (int dt = 0; dt < 16; ++dt) {
        // OUTACC for the tile completed at dt-1 (past the trailing barrier;
        // next g2t write is 2 barriers away -> race-free, overlaps GEN loads)
        if (dt && !(dt & 1)) outacc((dt >> 1) - 1);

        // GEN: wave wv owns c-block cb=wv; P[c, token] for d = dt*8+dd
        const int cb = wv;
        for (int dd = 0; dd < 8; ++dd) {
            int d = dt * 8 + dd;
            // bias: b2t[d][c], c = cb*16 + lq*4 + i -> one broadcast f32x4
            f32x4 acc = *(const f32x4*)&b2t[d * 128 + cb * 16 + lq * 4];
            for (int ks = 0; ks < 2; ++ks) {
                bf16x8 afr = *(const bf16x8*)&w2p[((cb * 128 + d) * 2 + ks) * 512 + lane * 8];
                acc = __builtin_amdgcn_mfma_f32_16x16x32_bf16(afr, hfr[ks], acc, 0, 0, 0);
            }
            // lane-linear pt: token=ln16, chunk=(c>>3)*8+dd, j=c&7
            uint2 wr;
            wr.x = pk2(acc[0], acc[1]);
            wr.y = pk2(acc[2], acc[3]);
            *(uint2*)&U.mp.pt[ln16 * 1032 + ((cb * 2 + (lq >> 1)) * 8 + dd) * 8 + (lq & 1) * 4] = wr;
        }
        __syncthreads();

        // CONSUME channel: 2 tokens per wave. Lanes n>=8 duplicate n-8's acc;
        // split gelu rows {0,1}/{2,3} across the halves (branchless).
        const int ddl = ln16 & 7;
        const bool hi = ln16 >= 8;
        for (int tt = 0; tt < 2; ++tt) {
            int t = wv * 2 + tt;
            bf16x8 bfr[4];
            for (int ks = 0; ks < 4; ++ks)
                bfr[ks] = *(const bf16x8*)&U.mp.pt[t * 1032 + (ks * 4 + lq) * 64 + ddl * 8];
            float mb = mb_s[dt * 8 + ddl];
            for (int mt = 0; mt < 2; ++mt) {
                f32x4 acc = {0.0f, 0.0f, 0.0f, 0.0f};
                for (int ks = 0; ks < 4; ++ks)
                    acc = __builtin_amdgcn_mfma_f32_16x16x32_bf16(xa[tt][mt][ks], bfr[ks], acc, 0, 0, 0);
                float va = hi ? acc[2] : acc[0];
                float vb = hi ? acc[3] : acc[1];
                float ga = gelu_fast(va + mb);
                float gb = gelu_fast(vb + mb);
                // g1s[t][d16][p]: d16 = (dt&1)*8+ddl; rows p0..p0+1 by lo half,
                // p0+2..p0+3 by hi half
                int p = mt * 16 + lq * 4 + (hi ? 2 : 0);
                *(uint32_t*)&U.mp.g1s[t * 640 + ((dt & 1) * 8 + ddl) * 40 + p] = pk2(ga, gb);
            }
        }

        // SPATIAL on odd dt: full 16-lane n over paired d16 = 0..15
        if (dt & 1) {
            __builtin_amdgcn_wave_barrier();          // order same-wave LDS W->R
            for (int tt = 0; tt < 2; ++tt) {
                int t = wv * 2 + tt;
                bf16x8 gfr = *(const bf16x8*)&U.mp.g1s[t * 640 + ln16 * 40 + lq * 8];
                for (int mt = 0; mt < 2; ++mt) {
                    f32x4 acc = {0.0f, 0.0f, 0.0f, 0.0f};
                    acc = __builtin_amdgcn_mfma_f32_16x16x32_bf16(sa[tt][mt], gfr, acc, 0, 0, 0);
                    float4 sbv = *(const float4*)&sb_s[mt * 16 + lq * 4];
                    float g0 = gelu_fast(acc[0] + sbv.x);
                    float g1 = gelu_fast(acc[1] + sbv.y);
                    float g2 = gelu_fast(acc[2] + sbv.z);
                    float g3 = gelu_fast(acc[3] + sbv.w);
                    uint2 wr;
                    wr.x = pk2(g0, g1);
                    wr.y = pk2(g2, g3);
                    // g2t[t][d16=ln16][o = mt*16+lq*4 ..+3], linear
                    *(uint2*)((char*)g2t + t * 1024 + ln16 * 64 + mt * 32 + lq * 8) = wr;
                }
            }
        }
        __syncthreads();
    }

    // last g2 tile (dt2 = 7), then out = aco + bo. D row = token, col = q.
    outacc(7);
    for (int n = 0; n < 2; ++n) {
        int q = (wv * 2 + n) * 16 + ln16;
        float bv = bo[q];
        for (int i = 0; i < 4; ++i) {
            int tok = tok0 + lq * 4 + i;
            out[(size_t)tok * 256 + q] = aco[n][i] + bv;
        }
    }
}

// ---------------------------------------------------------------------------
extern "C" void kernel_launch(void* const* d_in, const int* in_sizes, int n_in,
                              void* d_out, int out_size, void* d_ws, size_t ws_size,
                              hipStream_t stream) {
    const float* sampled = (const float*)d_in[0];
    const float* query   = (const float*)d_in[1];
    const float* ln_w    = (const float*)d_in[2];
    const float* ln_b    = (const float*)d_in[3];
    const float* w1      = (const float*)d_in[4];
    const float* b1      = (const float*)d_in[5];
    const float* w2      = (const float*)d_in[6];
    const float* b2      = (const float*)d_in[7];
    const float* m_beta  = (const float*)d_in[8];
    const float* s_beta  = (const float*)d_in[9];
    const float* wo      = (const float*)d_in[10];
    const float* bo      = (const float*)d_in[11];
    float* out = (float*)d_out;

    char* ws = (char*)d_ws;
    ushort* w2p  = (ushort*)(ws);                   // 2,097,152 B
    ushort* wop  = (ushort*)(ws + 2097152);         // 2,097,152 B
    ushort* w2sp = (ushort*)(ws + 4194304);         //   131,072 B
    ushort* w1p  = (ushort*)(ws + 4325376);         //    32,768 B
    float*  b2t  = (float*) (ws + 4358144);         //    65,536 B (total ~4.4 MB)

    prep<<<4096, 256, 0, stream>>>(w2, w1, wo, b2, w2p, w2sp, w1p, wop, b2t);
    fused<<<512, 512, 0, stream>>>(sampled, query, ln_w, ln_b, b1, b2,
                                   m_beta, s_beta, w2p, w2sp, w1p, b2t,
                                   wop, bo, out);
}

// Round 3
// 374.472 us; speedup vs baseline: 1.0489x; 1.0489x over previous
//
#include <hip/hip_runtime.h>
#include <cstdint>

// ---------------------------------------------------------------------------
// AdaptiveMixing fused kernel set, R8.
// R8 changes vs R7:
//  - g2t XOR swizzle restored (R6 retro-analysis: its swizzle WAS consistent;
//    NaN came from cvt_pk asm / VGPR cap, both still reverted). One shared
//    helper g2swz(t,d16,byte) = (t*1024+d16*64+byte) ^ (((t^d16)&7)<<4) used
//    by BOTH the spatial write and the outacc read -> consistency by
//    construction; bijective (bit-recovery argument verified); read goes
//    16-way -> ~2-way, write 8-way -> ~2-way.
//  - outacc: depth-1 register prefetch of wop B-frags (hides L2 latency
//    under the 2 MFMAs per d16 step).
//  - prep REWRITTEN for coalescing (theory: prep ~= the unexplained 143 us).
//    One thread per 8 output ushorts everywhere. wop (was 64x 4B-scattered
//    lines per wave-load): lanes map to dcol so the 8 strided reads per
//    thread coalesce into 256B segments across the wave; 16B/lane writes.
//    w2p/w2sp/w1p: 32B contiguous reads per thread, 1KB/wave linear writes.
//    b2t: coalesced-read float4 transpose. 1080 blocks x 256.
// Layouts (unchanged):
//   w2p  [cb][d][ks][lane][8], w2sp [g][ks][lane][8], w1p [nb][ks][lane][8],
//   wop  [kc5][nb][lane][8]  (kc5 = dcol of wo; k'' = o)
// MFMA 16x16x32_bf16: A/B: idx lane&15, k=(lane>>4)*8+j; C/D: col=lane&15,
// row=(lane>>4)*4+i.
// ---------------------------------------------------------------------------

typedef __bf16 bf16x8 __attribute__((ext_vector_type(8)));
typedef float  f32x4  __attribute__((ext_vector_type(4)));
typedef unsigned short ushort;
typedef ushort ushort8 __attribute__((ext_vector_type(8)));

#define TW 16     // tokens per fused workgroup

__device__ __forceinline__ ushort f2b(float f) {
    union { float f; uint32_t u; } v; v.f = f;
    uint32_t u = v.u;
    u += 0x7fffu + ((u >> 16) & 1u);   // RNE
    return (ushort)(u >> 16);
}
__device__ __forceinline__ uint32_t pk2(float a, float b) {
    return (uint32_t)f2b(a) | ((uint32_t)f2b(b) << 16);
}
// Abramowitz-Stegun 7.1.26 erf (|err|<=1.5e-7), branchless; gelu exact form.
__device__ __forceinline__ float gelu_fast(float x) {
    float z = fabsf(x) * 0.70710678118654752440f;
    float t = __builtin_amdgcn_rcpf(fmaf(0.3275911f, z, 1.0f));
    float p = t * fmaf(t, fmaf(t, fmaf(t, fmaf(t, 1.061405429f, -1.453152027f),
                                       1.421413741f), -0.284496736f), 0.254829592f);
    float e = __expf(-z * z);
    float erfv = copysignf(fmaf(-p, e, 1.0f), x);
    return 0.5f * x * (1.0f + erfv);
}

// g2t swizzle: shared by spatial write and outacc read. byte in [0,64).
// Bijective on the 16KB tile (bits 4-6 XORed by f(t,d16); recoverable).
__device__ __forceinline__ int g2swz(int t, int d16, int byte) {
    return (t * 1024 + d16 * 64 + byte) ^ (((t ^ d16) & 7) << 4);
}

// ---------------------------------------------------------------------------
// prep R8: coalesced permutes. 1080 blocks x 256 threads, block-range split:
//   [0,512)    w2p  : thread per (cb,d,ks,l) -> 2x float4 read, 16B write
//   [512,1024) wop  : thread per (q,o3,dcol) -> 8x stride-512B reads that
//                     coalesce across the wave (lane=dcol), 16B write
//   [1024,1056) w2sp: thread per (g,ks,l)
//   [1056,1064) w1p : thread per (nb,ks,l)
//   [1064,1080) b2t : float4 transpose, coalesced reads
__global__ void prep(const float* __restrict__ w2, const float* __restrict__ w1,
                     const float* __restrict__ wo, const float* __restrict__ b2,
                     ushort* __restrict__ w2p, ushort* __restrict__ w2sp,
                     ushort* __restrict__ w1p, ushort* __restrict__ wop,
                     float* __restrict__ b2t) {
    const int blk = blockIdx.x, tid = threadIdx.x;
    if (blk < 512) {
        // i8 = ((cb*128+d)*2+ks)*64 + l ; out = w2p[i8*8 .. +7]
        int i8 = blk * 256 + tid;
        int l = i8 & 63, ks = (i8 >> 6) & 1, d = (i8 >> 7) & 127, cb = i8 >> 14;
        int c = cb * 16 + (l & 15);
        const float* src = w2 + (size_t)(c * 128 + d) * 64 + ks * 32 + (l >> 4) * 8;
        float4 lo = *(const float4*)src, hi = *(const float4*)(src + 4);
        ushort8 u;
        u[0] = f2b(lo.x); u[1] = f2b(lo.y); u[2] = f2b(lo.z); u[3] = f2b(lo.w);
        u[4] = f2b(hi.x); u[5] = f2b(hi.y); u[6] = f2b(hi.z); u[7] = f2b(hi.w);
        *(ushort8*)&w2p[(size_t)i8 * 8] = u;
    } else if (blk < 1024) {
        // wop[kc5=dcol][nb=q>>4][l=(o3<<4)|(q&15)][j] = wo[q][o3*8+j][dcol]
        int t8 = (blk - 512) * 256 + tid;
        int dcol = t8 & 127, o3 = (t8 >> 7) & 3, q = t8 >> 9;
        const float* src = wo + (size_t)q * 4096 + o3 * 1024 + dcol;
        ushort8 u;
        #pragma unroll
        for (int j = 0; j < 8; ++j) u[j] = f2b(src[j * 128]);
        *(ushort8*)&wop[(size_t)dcol * 8192 + (q >> 4) * 512 + (q & 15) * 8 + o3 * 128] = u;
    } else if (blk < 1056) {
        // w2sp: i8 = g<<7 | ks<<6 | l
        int t = (blk - 1024) * 256 + tid;          // [0, 8192)
        int l = t & 63, ks = (t >> 6) & 1, g = t >> 7;
        const float* src = w2 + (size_t)(16384 + g * 16 + (l & 15)) * 64 +
                           ks * 32 + (l >> 4) * 8;
        float4 lo = *(const float4*)src, hi = *(const float4*)(src + 4);
        ushort8 u;
        u[0] = f2b(lo.x); u[1] = f2b(lo.y); u[2] = f2b(lo.z); u[3] = f2b(lo.w);
        u[4] = f2b(hi.x); u[5] = f2b(hi.y); u[6] = f2b(hi.z); u[7] = f2b(hi.w);
        *(ushort8*)&w2sp[(size_t)t * 8] = u;
    } else if (blk < 1064) {
        // w1p: i8 = nb<<9 | ks<<6 | l
        int t = (blk - 1056) * 256 + tid;          // [0, 2048)
        int l = t & 63, ks = (t >> 6) & 7, nb = t >> 9;
        const float* src = w1 + (nb * 16 + (l & 15)) * 256 + ks * 32 + (l >> 4) * 8;
        float4 lo = *(const float4*)src, hi = *(const float4*)(src + 4);
        ushort8 u;
        u[0] = f2b(lo.x); u[1] = f2b(lo.y); u[2] = f2b(lo.z); u[3] = f2b(lo.w);
        u[4] = f2b(hi.x); u[5] = f2b(hi.y); u[6] = f2b(hi.z); u[7] = f2b(hi.w);
        *(ushort8*)&w1p[(size_t)t * 8] = u;
    } else {
        // b2t[d][c] = b2[c][d]; lanes vary d -> coalesced reads
        int t = (blk - 1064) * 256 + tid;          // [0, 4096)
        int d = t & 127, c4 = t >> 7;
        float4 r;
        r.x = b2[(c4 * 4 + 0) * 128 + d];
        r.y = b2[(c4 * 4 + 1) * 128 + d];
        r.z = b2[(c4 * 4 + 2) * 128 + d];
        r.w = b2[(c4 * 4 + 3) * 128 + d];
        *(float4*)&b2t[d * 128 + c4 * 4] = r;
    }
}

// ---------------------------------------------------------------------------
__launch_bounds__(512, 2)
__global__ void fused(const float* __restrict__ sampled, const float* __restrict__ query,
                      const float* __restrict__ ln_w, const float* __restrict__ ln_b,
                      const float* __restrict__ b1, const float* __restrict__ b2,
                      const float* __restrict__ m_beta, const float* __restrict__ s_beta,
                      const ushort* __restrict__ w2p, const ushort* __restrict__ w2sp,
                      const ushort* __restrict__ w1p, const float* __restrict__ b2t,
                      const ushort* __restrict__ wop, const float* __restrict__ bo,
                      float* __restrict__ out) {
    __shared__ ushort Hb[TW * 64];                       // h bf16 [t][64]
    __shared__ union {
        ushort qn[TW * 264];                             // phase 1: LN out
        ushort smT[TW * 1032];                           // phase 2: sm [t][o*32+p]
        struct {
            ushort pt[TW * 1032];                        // [t][chunk(c>>3,dd)][c&7]
            ushort g1s[TW * 640];                        // [t][d16*40+p]
        } mp;                                            // main loop
    } U;
    // g2 tile, lives across 2 barriers (spatial writes odd dt, OUTACC reads
    // next even dt) -> own allocation. XOR-swizzled via g2swz (both sides).
    __shared__ __align__(16) ushort g2t[TW * 16 * 32];   // 16384 B
    __shared__ float mb_s[128];
    __shared__ float sb_s[32];

    const int tid  = threadIdx.x;
    const int wv   = tid >> 6;          // wave 0..7
    const int lane = tid & 63;
    const int lq   = lane >> 4;         // quad
    const int ln16 = lane & 15;
    const int tok0 = blockIdx.x * TW;

    if (tid < 128) mb_s[tid] = m_beta[tid];
    else if (tid < 160) sb_s[tid - 128] = s_beta[tid - 128];

    // ---- step 1: LayerNorm, 2 tokens per wave; qn -> LDS bf16 (row 264)
    for (int tt = 0; tt < 2; ++tt) {
        int t = wv * 2 + tt;
        const float* q = query + (size_t)(tok0 + t) * 256;
        float2 a = *(const float2*)(q + 2 * lane);
        float2 b = *(const float2*)(q + 128 + 2 * lane);
        float s = a.x + a.y + b.x + b.y;
        for (int off = 1; off < 64; off <<= 1) s += __shfl_xor(s, off);
        float mu = s * (1.0f / 256.0f);
        float d0 = a.x - mu, d1 = a.y - mu, d2 = b.x - mu, d3 = b.y - mu;
        float ss = d0 * d0 + d1 * d1 + d2 * d2 + d3 * d3;
        for (int off = 1; off < 64; off <<= 1) ss += __shfl_xor(ss, off);
        float rstd = rsqrtf(ss * (1.0f / 256.0f) + 1e-6f);
        int i0 = 2 * lane, i1 = 2 * lane + 128;
        float q0 = d0 * rstd * ln_w[i0]     + ln_b[i0];
        float q1 = d1 * rstd * ln_w[i0 + 1] + ln_b[i0 + 1];
        float q2 = d2 * rstd * ln_w[i1]     + ln_b[i1];
        float q3 = d3 * rstd * ln_w[i1 + 1] + ln_b[i1 + 1];
        *(uint32_t*)&U.qn[t * 264 + i0] = pk2(q0, q1);
        *(uint32_t*)&U.qn[t * 264 + i1] = pk2(q2, q3);
    }
    __syncthreads();

    // ---- step 2: h[16 tok][64] = qn @ w1^T + b1 (waves 0..3)
    if (wv < 4) {
        int nb = wv;
        f32x4 acc = {0.0f, 0.0f, 0.0f, 0.0f};
        for (int ks = 0; ks < 8; ++ks) {
            bf16x8 afr = *(const bf16x8*)&U.qn[ln16 * 264 + ks * 32 + lq * 8];
            bf16x8 bfr = *(const bf16x8*)&w1p[(nb * 8 + ks) * 512 + lane * 8];
            acc = __builtin_amdgcn_mfma_f32_16x16x32_bf16(afr, bfr, acc, 0, 0, 0);
        }
        float bias = b1[nb * 16 + ln16];
        for (int i = 0; i < 4; ++i) {
            int t = lq * 4 + i;                      // D row = token
            Hb[t * 64 + nb * 16 + ln16] = f2b(acc[i] + bias);
        }
    }
    __syncthreads();

    // ---- step 3: H B-frags; sm generation -> smT; x A-frag hoist
    bf16x8 hfr[2];
    hfr[0] = *(const bf16x8*)&Hb[ln16 * 64 + 0 + lq * 8];
    hfr[1] = *(const bf16x8*)&Hb[ln16 * 64 + 32 + lq * 8];

    for (int gi = 0; gi < 8; ++gi) {                 // sm rows 16384 + g*16 + m
        int g = wv * 8 + gi;
        f32x4 acc = *(const f32x4*)&b2[16384 + g * 16 + lq * 4];
        for (int ks = 0; ks < 2; ++ks) {
            bf16x8 afr = *(const bf16x8*)&w2sp[(g * 2 + ks) * 512 + lane * 8];
            acc = __builtin_amdgcn_mfma_f32_16x16x32_bf16(afr, hfr[ks], acc, 0, 0, 0);
        }
        int o = g >> 1;
        int p0 = (g & 1) * 16 + lq * 4;
        uint2 wr;
        wr.x = pk2(acc[0], acc[1]);
        wr.y = pk2(acc[2], acc[3]);
        *(uint2*)&U.smT[ln16 * 1032 + o * 32 + p0] = wr;   // token-major
    }

    bf16x8 xa[2][2][4];                              // x A-frags [tt][p-half][ks]
    for (int tt = 0; tt < 2; ++tt) {
        const float* xp = sampled + (size_t)(tok0 + wv * 2 + tt) * 4096;
        for (int mt = 0; mt < 2; ++mt) {
            int p = mt * 16 + ln16;
            for (int ks = 0; ks < 4; ++ks) {
                int c = ks * 32 + lq * 8;
                float4 lo = *(const float4*)(xp + p * 128 + c);
                float4 hi = *(const float4*)(xp + p * 128 + c + 4);
                ushort8 u;
                u[0] = f2b(lo.x); u[1] = f2b(lo.y); u[2] = f2b(lo.z); u[3] = f2b(lo.w);
                u[4] = f2b(hi.x); u[5] = f2b(hi.y); u[6] = f2b(hi.z); u[7] = f2b(hi.w);
                xa[tt][mt][ks] = __builtin_bit_cast(bf16x8, u);
            }
        }
    }
    __syncthreads();

    // ---- step 4: sm A-frags (K=32) for this wave's 2 tokens
    bf16x8 sa[2][2];
    for (int tt = 0; tt < 2; ++tt) {
        int t = wv * 2 + tt;
        for (int mt = 0; mt < 2; ++mt)
            sa[tt][mt] = *(const bf16x8*)&U.smT[t * 1032 + (mt * 16 + ln16) * 32 + lq * 8];
    }
    __syncthreads();    // smT dead; pt/g1s alias it from here on

    // out-projection accumulator: 16 tok x 32 q per wave (nb = 2wv, 2wv+1)
    f32x4 aco[2] = {(f32x4){0.0f, 0.0f, 0.0f, 0.0f}, (f32x4){0.0f, 0.0f, 0.0f, 0.0f}};

    // OUTACC(dt2): aco += g2t(tile dt2) @ wop. A: row=t(ln16), k=o(lq*8+j);
    // B: wop[kc5=dt2*16+d16][nb][lane][8]. Depth-1 register prefetch of the
    // wop B-frags hides L2 latency under the 2 MFMAs per step.
    auto outacc = [&](int dt2) {
        const ushort* wb = wop + ((size_t)(dt2 * 16) * 16 + wv * 2) * 512 + lane * 8;
        bf16x8 nb0 = *(const bf16x8*)(wb);
        bf16x8 nb1 = *(const bf16x8*)(wb + 512);
        for (int d16 = 0; d16 < 16; ++d16) {
            bf16x8 b0 = nb0, b1 = nb1;
            if (d16 < 15) {
                nb0 = *(const bf16x8*)(wb + (size_t)(d16 + 1) * 8192);
                nb1 = *(const bf16x8*)(wb + (size_t)(d16 + 1) * 8192 + 512);
            }
            bf16x8 afr = *(const bf16x8*)((const char*)g2t + g2swz(ln16, d16, lq * 16));
            aco[0] = __builtin_amdgcn_mfma_f32_16x16x32_bf16(afr, b0, aco[0], 0, 0, 0);
            aco[1] = __builtin_amdgcn_mfma_f32_16x16x32_bf16(afr, b1, aco[1], 0, 0, 0);
        }
    };

    // ---- main loop over 16 d-tiles of width 8; spatial every 2nd tile
    for (int dt = 0; dt < 16; ++dt) {
        // OUTACC for the tile completed at dt-1 (past the trailing barrier;
        // next g2t write is 2 barriers away -> race-free, overlaps GEN loads)
        if (dt && !(dt & 1)) outacc((dt >> 1) - 1);

        // GEN: wave wv owns c-block cb=wv; P[c, token] for d = dt*8+dd
        const int cb = wv;
        for (int dd = 0; dd < 8; ++dd) {
            int d = dt * 8 + dd;
            // bias: b2t[d][c], c = cb*16 + lq*4 + i -> one broadcast f32x4
            f32x4 acc = *(const f32x4*)&b2t[d * 128 + cb * 16 + lq * 4];
            for (int ks = 0; ks < 2; ++ks) {
                bf16x8 afr = *(const bf16x8*)&w2p[((cb * 128 + d) * 2 + ks) * 512 + lane * 8];
                acc = __builtin_amdgcn_mfma_f32_16x16x32_bf16(afr, hfr[ks], acc, 0, 0, 0);
            }
            // lane-linear pt: token=ln16, chunk=(c>>3)*8+dd, j=c&7
            uint2 wr;
            wr.x = pk2(acc[0], acc[1]);
            wr.y = pk2(acc[2], acc[3]);
            *(uint2*)&U.mp.pt[ln16 * 1032 + ((cb * 2 + (lq >> 1)) * 8 + dd) * 8 + (lq & 1) * 4] = wr;
        }
        __syncthreads();

        // CONSUME channel: 2 tokens per wave. Lanes n>=8 duplicate n-8's acc;
        // split gelu rows {0,1}/{2,3} across the halves (branchless).
        const int ddl = ln16 & 7;
        const bool hi = ln16 >= 8;
        for (int tt = 0; tt < 2; ++tt) {
            int t = wv * 2 + tt;
            bf16x8 bfr[4];
            for (int ks = 0; ks < 4; ++ks)
                bfr[ks] = *(const bf16x8*)&U.mp.pt[t * 1032 + (ks * 4 + lq) * 64 + ddl * 8];
            float mb = mb_s[dt * 8 + ddl];
            for (int mt = 0; mt < 2; ++mt) {
                f32x4 acc = {0.0f, 0.0f, 0.0f, 0.0f};
                for (int ks = 0; ks < 4; ++ks)
                    acc = __builtin_amdgcn_mfma_f32_16x16x32_bf16(xa[tt][mt][ks], bfr[ks], acc, 0, 0, 0);
                float va = hi ? acc[2] : acc[0];
                float vb = hi ? acc[3] : acc[1];
                float ga = gelu_fast(va + mb);
                float gb = gelu_fast(vb + mb);
                // g1s[t][d16][p]: d16 = (dt&1)*8+ddl; rows p0..p0+1 by lo half,
                // p0+2..p0+3 by hi half
                int p = mt * 16 + lq * 4 + (hi ? 2 : 0);
                *(uint32_t*)&U.mp.g1s[t * 640 + ((dt & 1) * 8 + ddl) * 40 + p] = pk2(ga, gb);
            }
        }

        // SPATIAL on odd dt: full 16-lane n over paired d16 = 0..15
        if (dt & 1) {
            __builtin_amdgcn_wave_barrier();          // order same-wave LDS W->R
            for (int tt = 0; tt < 2; ++tt) {
                int t = wv * 2 + tt;
                bf16x8 gfr = *(const bf16x8*)&U.mp.g1s[t * 640 + ln16 * 40 + lq * 8];
                for (int mt = 0; mt < 2; ++mt) {
                    f32x4 acc = {0.0f, 0.0f, 0.0f, 0.0f};
                    acc = __builtin_amdgcn_mfma_f32_16x16x32_bf16(sa[tt][mt], gfr, acc, 0, 0, 0);
                    float4 sbv = *(const float4*)&sb_s[mt * 16 + lq * 4];
                    float g0 = gelu_fast(acc[0] + sbv.x);
                    float g1 = gelu_fast(acc[1] + sbv.y);
                    float g2 = gelu_fast(acc[2] + sbv.z);
                    float g3 = gelu_fast(acc[3] + sbv.w);
                    uint2 wr;
                    wr.x = pk2(g0, g1);
                    wr.y = pk2(g2, g3);
                    // g2t[t][d16=ln16][o = mt*16+lq*4 ..+3], swizzled (8B write:
                    // byte bit3 = lq&1 untouched; XOR hits bits 4-6 only)
                    *(uint2*)((char*)g2t + g2swz(t, ln16, mt * 32 + lq * 8)) = wr;
                }
            }
        }
        __syncthreads();
    }

    // last g2 tile (dt2 = 7), then out = aco + bo. D row = token, col = q.
    outacc(7);
    for (int n = 0; n < 2; ++n) {
        int q = (wv * 2 + n) * 16 + ln16;
        float bv = bo[q];
        for (int i = 0; i < 4; ++i) {
            int tok = tok0 + lq * 4 + i;
            out[(size_t)tok * 256 + q] = aco[n][i] + bv;
        }
    }
}

// ---------------------------------------------------------------------------
extern "C" void kernel_launch(void* const* d_in, const int* in_sizes, int n_in,
                              void* d_out, int out_size, void* d_ws, size_t ws_size,
                              hipStream_t stream) {
    const float* sampled = (const float*)d_in[0];
    const float* query   = (const float*)d_in[1];
    const float* ln_w    = (const float*)d_in[2];
    const float* ln_b    = (const float*)d_in[3];
    const float* w1      = (const float*)d_in[4];
    const float* b1      = (const float*)d_in[5];
    const float* w2      = (const float*)d_in[6];
    const float* b2      = (const float*)d_in[7];
    const float* m_beta  = (const float*)d_in[8];
    const float* s_beta  = (const float*)d_in[9];
    const float* wo      = (const float*)d_in[10];
    const float* bo      = (const float*)d_in[11];
    float* out = (float*)d_out;

    char* ws = (char*)d_ws;
    ushort* w2p  = (ushort*)(ws);                   // 2,097,152 B
    ushort* wop  = (ushort*)(ws + 2097152);         // 2,097,152 B
    ushort* w2sp = (ushort*)(ws + 4194304);         //   131,072 B
    ushort* w1p  = (ushort*)(ws + 4325376);         //    32,768 B
    float*  b2t  = (float*) (ws + 4358144);         //    65,536 B (total ~4.4 MB)

    prep<<<1080, 256, 0, stream>>>(w2, w1, wo, b2, w2p, w2sp, w1p, wop, b2t);
    fused<<<512, 512, 0, stream>>>(sampled, query, ln_w, ln_b, b1, b2,
                                   m_beta, s_beta, w2p, w2sp, w1p, b2t,
                                   wop, bo, out);
}